// Round 1
// baseline (255.977 us; speedup 1.0000x reference)
//
#include <hip/hip_runtime.h>

// Problem constants (from reference)
#define NF 8
#define NK 16
#define NY 16
#define NX 16
#define NP 32
#define NT 8
#define NYX 256   // NY*NX
#define NPT 256   // NP*NT
#define NB 64

// ---------------------------------------------------------------------------
// Kernel 1: per (f,k) build separable factors and the normalization integral.
//   A'[fk][yx] = klat[y]*klon[x] / (sum_{yxpt} kp*qw + 1e-4)
//   Bm[fk][pt] = klev[p]*ktime[t]
// One workgroup (256 threads) per fk; thread id == pt for the integral pass.
// ---------------------------------------------------------------------------
__global__ __launch_bounds__(256) void prep_kernel(
    const float* __restrict__ qw,
    const float* __restrict__ mu_lat, const float* __restrict__ ls_lat,
    const float* __restrict__ mu_lon, const float* __restrict__ ls_lon,
    const float* __restrict__ mu_lev, const float* __restrict__ ls_lev,
    const float* __restrict__ lt_time,
    float* __restrict__ Ag, float* __restrict__ Bg)
{
    const int fk  = blockIdx.x;     // 0..127  (= f*NK + k)
    const int tid = threadIdx.x;    // 0..255

    __shared__ float klat[NY];
    __shared__ float klon[NX];
    __shared__ float klev[NP];
    __shared__ float ktim[NT];
    __shared__ float wred[4];
    __shared__ float s_inv;

    if (tid < 16) {
        float c = -1.0f + 2.0f * (float)tid / 15.0f;
        float d = (c - mu_lat[fk]) / expf(ls_lat[fk]);
        klat[tid] = expf(-0.5f * d * d);
    } else if (tid < 32) {
        int i = tid - 16;
        float c = -1.0f + 2.0f * (float)i / 15.0f;
        float d = (c - mu_lon[fk]) / expf(ls_lon[fk]);
        klon[i] = expf(-0.5f * d * d);
    } else if (tid < 64) {
        int i = tid - 32;
        float c = -1.0f + 2.0f * (float)i / 31.0f;
        float d = (c - mu_lev[fk]) / expf(ls_lev[fk]);
        klev[i] = expf(-0.5f * d * d);
    } else if (tid < 72) {
        int i = tid - 64;
        float tau = expf(lt_time[fk]) + 1e-6f;
        ktim[i] = expf(-(float)i / tau);
    }
    __syncthreads();

    const int pt = tid;
    const float bm = klev[pt >> 3] * ktim[pt & 7];

    // integrated = sum_{yx,pt} klat*klon*klev*ktime*qw
    float acc = 0.0f;
    for (int e = 0; e < NYX; ++e) {
        float a = klat[e >> 4] * klon[e & 15];       // LDS broadcast
        acc = fmaf(qw[e * NPT + pt] * bm, a, acc);   // coalesced qw read
    }
    // wave reduce (64 lanes)
    #pragma unroll
    for (int s = 32; s > 0; s >>= 1) acc += __shfl_xor(acc, s, 64);
    if ((tid & 63) == 0) wred[tid >> 6] = acc;
    __syncthreads();
    if (tid == 0) {
        float integ = wred[0] + wred[1] + wred[2] + wred[3] + 1e-4f;
        s_inv = 1.0f / integ;
    }
    __syncthreads();

    Bg[fk * NPT + pt] = bm;
    Ag[fk * NYX + tid] = klat[tid >> 4] * klon[tid & 15] * s_inv;
}

// ---------------------------------------------------------------------------
// Kernel 2: main streaming reduction.
//   features[b,f,k] = sum_{yx,pt} patch[b,f,yx,pt]*qw[yx,pt]*A'[f,k,yx]*Bm[f,k,pt]
// Grid (chunk=4, f=8, b=64); block 256 = 4 waves. Each wave owns 16 yx rows;
// lane l owns pt = 4l..4l+3 (coalesced float4). Bm fragment lives in VGPRs.
// ---------------------------------------------------------------------------
__global__ __launch_bounds__(256) void main_kernel(
    const float* __restrict__ patch,
    const float* __restrict__ qw,
    const float* __restrict__ Ag,
    const float* __restrict__ Bg,
    float* __restrict__ out)
{
    const int chunk = blockIdx.x;   // 0..3   (yx chunk of 64)
    const int f     = blockIdx.y;   // 0..7
    const int b     = blockIdx.z;   // 0..63
    const int tid   = threadIdx.x;
    const int lane  = tid & 63;
    const int wid   = tid >> 6;     // 0..3

    // Bm fragment: 4 floats per k per lane -> 64 VGPRs
    float4 bm4[NK];
    #pragma unroll
    for (int k = 0; k < NK; ++k)
        bm4[k] = *reinterpret_cast<const float4*>(Bg + ((f * NK + k) << 8) + (lane << 2));

    float acc[NK];
    #pragma unroll
    for (int k = 0; k < NK; ++k) acc[k] = 0.0f;

    const size_t pb  = ((size_t)(b * NF + f)) << 16;   // *65536
    const int   yx0  = chunk * 64 + wid * 16;

    for (int g = 0; g < 4; ++g) {
        const int yx = yx0 + g * 4;
        float4 wp[4];
        #pragma unroll
        for (int j = 0; j < 4; ++j) {
            const int off = ((yx + j) << 8) + (lane << 2);
            float4 p = *reinterpret_cast<const float4*>(patch + pb + off);
            float4 q = *reinterpret_cast<const float4*>(qw + off);
            wp[j].x = p.x * q.x;
            wp[j].y = p.y * q.y;
            wp[j].z = p.z * q.z;
            wp[j].w = p.w * q.w;
        }
        #pragma unroll
        for (int k = 0; k < NK; ++k) {
            const float4 a4 = *reinterpret_cast<const float4*>(Ag + ((f * NK + k) << 8) + yx);
            float i0 = fmaf(wp[0].x, bm4[k].x, fmaf(wp[0].y, bm4[k].y, fmaf(wp[0].z, bm4[k].z, wp[0].w * bm4[k].w)));
            float i1 = fmaf(wp[1].x, bm4[k].x, fmaf(wp[1].y, bm4[k].y, fmaf(wp[1].z, bm4[k].z, wp[1].w * bm4[k].w)));
            float i2 = fmaf(wp[2].x, bm4[k].x, fmaf(wp[2].y, bm4[k].y, fmaf(wp[2].z, bm4[k].z, wp[2].w * bm4[k].w)));
            float i3 = fmaf(wp[3].x, bm4[k].x, fmaf(wp[3].y, bm4[k].y, fmaf(wp[3].z, bm4[k].z, wp[3].w * bm4[k].w)));
            float s = fmaf(a4.x, i0, fmaf(a4.y, i1, fmaf(a4.z, i2, a4.w * i3)));
            acc[k] += s;
        }
    }

    // cross-lane reduce (all 64 lanes hold partials over pt and yx subsets)
    #pragma unroll
    for (int k = 0; k < NK; ++k) {
        float v = acc[k];
        #pragma unroll
        for (int s = 32; s > 0; s >>= 1) v += __shfl_xor(v, s, 64);
        acc[k] = v;
    }

    if (lane == 0) {
        #pragma unroll
        for (int k = 0; k < NK; ++k)
            atomicAdd(out + (b * NF + f) * NK + k, acc[k]);
    }
}

extern "C" void kernel_launch(void* const* d_in, const int* in_sizes, int n_in,
                              void* d_out, int out_size, void* d_ws, size_t ws_size,
                              hipStream_t stream)
{
    const float* patch   = (const float*)d_in[0];
    const float* qw      = (const float*)d_in[1];
    const float* mu_lat  = (const float*)d_in[2];
    const float* ls_lat  = (const float*)d_in[3];
    const float* mu_lon  = (const float*)d_in[4];
    const float* ls_lon  = (const float*)d_in[5];
    const float* mu_lev  = (const float*)d_in[6];
    const float* ls_lev  = (const float*)d_in[7];
    const float* lt_time = (const float*)d_in[8];
    float* out = (float*)d_out;

    float* Ag = (float*)d_ws;                 // 128*256 floats = 128 KiB
    float* Bg = Ag + NF * NK * NYX;           // 128*256 floats = 128 KiB

    // out is poisoned with 0xAA before every timed launch -> zero it (atomics)
    hipMemsetAsync(d_out, 0, (size_t)out_size * sizeof(float), stream);

    prep_kernel<<<dim3(NF * NK), dim3(256), 0, stream>>>(
        qw, mu_lat, ls_lat, mu_lon, ls_lon, mu_lev, ls_lev, lt_time, Ag, Bg);

    main_kernel<<<dim3(4, NF, NB), dim3(256), 0, stream>>>(patch, qw, Ag, Bg, out);
}

// Round 8
// 230.324 us; speedup vs baseline: 1.1114x; 1.1114x over previous
//
#include <hip/hip_runtime.h>

// Problem constants (from reference)
#define NF 8
#define NK 16
#define NY 16
#define NX 16
#define NP 32
#define NT 8
#define NYX 256   // NY*NX
#define NPT 256   // NP*NT
#define NB 64

// ---------------------------------------------------------------------------
// Kernel 1: per (f,k) build separable factors and the normalization integral.
//   At[f][yx][k] = klat[y]*klon[x] / (integral + 1e-4)    (transposed layout!)
//   Bg[fk][pt]   = klev[p]*ktime[t]
// One workgroup (256 threads = 4 waves) per fk. Integral via per-lane float4
// partial dots (coalesced qw reads) -> wave shuffle reduce -> LDS combine.
// ---------------------------------------------------------------------------
__global__ __launch_bounds__(256) void prep_kernel(
    const float* __restrict__ qw,
    const float* __restrict__ mu_lat, const float* __restrict__ ls_lat,
    const float* __restrict__ mu_lon, const float* __restrict__ ls_lon,
    const float* __restrict__ mu_lev, const float* __restrict__ ls_lev,
    const float* __restrict__ lt_time,
    float* __restrict__ At,   // [NF][NYX][NK]
    float* __restrict__ Bg)   // [NF*NK][NPT]
{
    const int fk   = blockIdx.x;     // f*NK + k
    const int f    = fk >> 4;
    const int k    = fk & 15;
    const int tid  = threadIdx.x;
    const int lane = tid & 63;
    const int wid  = tid >> 6;

    __shared__ float klat[NY], klon[NX], klev[NP], ktim[NT];
    __shared__ float wred[4];
    __shared__ float s_inv;

    if (tid < 16) {
        float c = -1.0f + 2.0f * (float)tid / 15.0f;
        float d = (c - mu_lat[fk]) / expf(ls_lat[fk]);
        klat[tid] = expf(-0.5f * d * d);
    } else if (tid < 32) {
        int i = tid - 16;
        float c = -1.0f + 2.0f * (float)i / 15.0f;
        float d = (c - mu_lon[fk]) / expf(ls_lon[fk]);
        klon[i] = expf(-0.5f * d * d);
    } else if (tid < 64) {
        int i = tid - 32;
        float c = -1.0f + 2.0f * (float)i / 31.0f;
        float d = (c - mu_lev[fk]) / expf(ls_lev[fk]);
        klev[i] = expf(-0.5f * d * d);
    } else if (tid < 72) {
        int i = tid - 64;
        float tau = expf(lt_time[fk]) + 1e-6f;
        ktim[i] = expf(-(float)i / tau);
    }
    __syncthreads();

    // Per-lane Bm fragment: pt = lane*4 + j  ->  p = lane>>1 (same for j=0..3),
    // t = (lane&1)*4 + j.
    const float kl = klev[lane >> 1];
    float4 bm4;
    bm4.x = kl * ktim[(lane & 1) * 4 + 0];
    bm4.y = kl * ktim[(lane & 1) * 4 + 1];
    bm4.z = kl * ktim[(lane & 1) * 4 + 2];
    bm4.w = kl * ktim[(lane & 1) * 4 + 3];

    // integral: wave wid handles rows yx = wid*64 .. wid*64+63, coalesced
    float acc = 0.0f;
    #pragma unroll 4
    for (int i = 0; i < 64; ++i) {
        const int yx = wid * 64 + i;                          // wave-uniform
        float4 q4 = *reinterpret_cast<const float4*>(qw + yx * NPT + (lane << 2));
        float s = fmaf(q4.x, bm4.x, fmaf(q4.y, bm4.y, fmaf(q4.z, bm4.z, q4.w * bm4.w)));
        float a = klat[yx >> 4] * klon[yx & 15];              // LDS broadcast
        acc = fmaf(a, s, acc);
    }
    #pragma unroll
    for (int s = 32; s; s >>= 1) acc += __shfl_xor(acc, s, 64);
    if (lane == 0) wred[wid] = acc;
    __syncthreads();
    if (tid == 0) s_inv = 1.0f / (wred[0] + wred[1] + wred[2] + wred[3] + 1e-4f);
    __syncthreads();

    // outputs: Bg coalesced; At transposed (strided scalar writes, tiny)
    Bg[fk * NPT + tid] = klev[tid >> 3] * ktim[tid & 7];
    At[(f * NYX + tid) * NK + k] = klat[tid >> 4] * klon[tid & 15] * s_inv;
}

// ---------------------------------------------------------------------------
// Kernel 2: main streaming reduction. One block = one (b,f).
//   acc4[k] (float4 over this lane's 4 pt's) += A'[k,yx] * (patch*qw)4
//   epilogue: v[k] = dot(acc4[k], Bm4[k]); reduce lanes+waves; direct store.
// 16 FMA per patch element (lower bound) + 1 mul; no atomics, no memset.
// ---------------------------------------------------------------------------
__global__ __launch_bounds__(256) void main_kernel(
    const float* __restrict__ patch,
    const float* __restrict__ qw,
    const float* __restrict__ At,   // [NF][NYX][NK]
    const float* __restrict__ Bg,   // [NF*NK][NPT]
    float* __restrict__ out)
{
    const int bf   = blockIdx.x;    // b*NF + f  (patch is laid out exactly so)
    const int f    = bf & 7;
    const int tid  = threadIdx.x;
    const int lane = tid & 63;
    const int wid  = tid >> 6;

    // Stage A'[f] (16 KB) into LDS: inner-loop reads become uniform
    // ds_read_b128 broadcasts (conflict-free).
    __shared__ float sA[NYX * NK];
    {
        const float4* src = reinterpret_cast<const float4*>(At + f * NYX * NK);
        float4* dst = reinterpret_cast<float4*>(sA);
        #pragma unroll
        for (int j = 0; j < 4; ++j)
            dst[tid + 256 * j] = src[tid + 256 * j];
    }
    __syncthreads();

    float4 acc[NK];
    #pragma unroll
    for (int k = 0; k < NK; ++k) acc[k] = make_float4(0.f, 0.f, 0.f, 0.f);

    const float* pbase = patch + ((size_t)bf << 16);
    const int row0 = wid * 64;     // each wave streams 64 contiguous rows (64 KB)

    #pragma unroll 8
    for (int i = 0; i < 64; ++i) {
        const int yx  = row0 + i;
        const int off = (yx << 8) + (lane << 2);
        float4 p4 = *reinterpret_cast<const float4*>(pbase + off);
        float4 q4 = *reinterpret_cast<const float4*>(qw + off);
        float4 wp;
        wp.x = p4.x * q4.x; wp.y = p4.y * q4.y;
        wp.z = p4.z * q4.z; wp.w = p4.w * q4.w;
        const float4* arow = reinterpret_cast<const float4*>(sA + (yx << 4));
        #pragma unroll
        for (int kq = 0; kq < 4; ++kq) {
            const float4 a4 = arow[kq];     // uniform LDS broadcast
            float4& c0 = acc[kq * 4 + 0];
            float4& c1 = acc[kq * 4 + 1];
            float4& c2 = acc[kq * 4 + 2];
            float4& c3 = acc[kq * 4 + 3];
            c0.x = fmaf(a4.x, wp.x, c0.x); c0.y = fmaf(a4.x, wp.y, c0.y);
            c0.z = fmaf(a4.x, wp.z, c0.z); c0.w = fmaf(a4.x, wp.w, c0.w);
            c1.x = fmaf(a4.y, wp.x, c1.x); c1.y = fmaf(a4.y, wp.y, c1.y);
            c1.z = fmaf(a4.y, wp.z, c1.z); c1.w = fmaf(a4.y, wp.w, c1.w);
            c2.x = fmaf(a4.z, wp.x, c2.x); c2.y = fmaf(a4.z, wp.y, c2.y);
            c2.z = fmaf(a4.z, wp.z, c2.z); c2.w = fmaf(a4.z, wp.w, c2.w);
            c3.x = fmaf(a4.w, wp.x, c3.x); c3.y = fmaf(a4.w, wp.y, c3.y);
            c3.z = fmaf(a4.w, wp.z, c3.z); c3.w = fmaf(a4.w, wp.w, c3.w);
        }
    }

    // Epilogue: dot with Bm fragment, reduce 64 lanes, then 4 waves via LDS.
    __shared__ float red[4][NK];
    float v[NK];
    #pragma unroll
    for (int k = 0; k < NK; ++k) {
        const float4 bm4 = *reinterpret_cast<const float4*>(
            Bg + ((f * NK + k) << 8) + (lane << 2));
        float s = fmaf(acc[k].x, bm4.x, fmaf(acc[k].y, bm4.y,
                  fmaf(acc[k].z, bm4.z, acc[k].w * bm4.w)));
        #pragma unroll
        for (int t = 32; t; t >>= 1) s += __shfl_xor(s, t, 64);
        v[k] = s;
    }
    if (lane == 0) {
        #pragma unroll
        for (int k = 0; k < NK; ++k) red[wid][k] = v[k];
    }
    __syncthreads();
    if (tid < NK)
        out[bf * NK + tid] = red[0][tid] + red[1][tid] + red[2][tid] + red[3][tid];
}

extern "C" void kernel_launch(void* const* d_in, const int* in_sizes, int n_in,
                              void* d_out, int out_size, void* d_ws, size_t ws_size,
                              hipStream_t stream)
{
    const float* patch   = (const float*)d_in[0];
    const float* qw      = (const float*)d_in[1];
    const float* mu_lat  = (const float*)d_in[2];
    const float* ls_lat  = (const float*)d_in[3];
    const float* mu_lon  = (const float*)d_in[4];
    const float* ls_lon  = (const float*)d_in[5];
    const float* mu_lev  = (const float*)d_in[6];
    const float* ls_lev  = (const float*)d_in[7];
    const float* lt_time = (const float*)d_in[8];
    float* out = (float*)d_out;

    float* At = (float*)d_ws;                 // 8*256*16 floats = 128 KiB
    float* Bg = At + NF * NYX * NK;           // 128*256 floats  = 128 KiB

    prep_kernel<<<dim3(NF * NK), dim3(256), 0, stream>>>(
        qw, mu_lat, ls_lat, mu_lon, ls_lon, mu_lev, ls_lev, lt_time, At, Bg);

    main_kernel<<<dim3(NB * NF), dim3(256), 0, stream>>>(patch, qw, At, Bg, out);
}

// Round 9
// 218.874 us; speedup vs baseline: 1.1695x; 1.0523x over previous
//
#include <hip/hip_runtime.h>

// Problem constants (from reference)
#define NF 8
#define NK 16
#define NY 16
#define NX 16
#define NP 32
#define NT 8
#define NYX 256   // NY*NX
#define NPT 256   // NP*NT
#define NB 64

// ---------------------------------------------------------------------------
// Kernel 1: per (f,k) build separable factors and the normalization integral.
//   At[f][yx][k] = klat[y]*klon[x] / (integral + 1e-4)    (transposed layout!)
//   Bg[fk][pt]   = klev[p]*ktime[t]
// One workgroup (256 threads = 4 waves) per fk. Integral via per-lane float4
// partial dots (coalesced qw reads) -> wave shuffle reduce -> LDS combine.
// ---------------------------------------------------------------------------
__global__ __launch_bounds__(256) void prep_kernel(
    const float* __restrict__ qw,
    const float* __restrict__ mu_lat, const float* __restrict__ ls_lat,
    const float* __restrict__ mu_lon, const float* __restrict__ ls_lon,
    const float* __restrict__ mu_lev, const float* __restrict__ ls_lev,
    const float* __restrict__ lt_time,
    float* __restrict__ At,   // [NF][NYX][NK]
    float* __restrict__ Bg)   // [NF*NK][NPT]
{
    const int fk   = blockIdx.x;     // f*NK + k
    const int f    = fk >> 4;
    const int k    = fk & 15;
    const int tid  = threadIdx.x;
    const int lane = tid & 63;
    const int wid  = tid >> 6;

    __shared__ float klat[NY], klon[NX], klev[NP], ktim[NT];
    __shared__ float wred[4];
    __shared__ float s_inv;

    if (tid < 16) {
        float c = -1.0f + 2.0f * (float)tid / 15.0f;
        float d = (c - mu_lat[fk]) / expf(ls_lat[fk]);
        klat[tid] = expf(-0.5f * d * d);
    } else if (tid < 32) {
        int i = tid - 16;
        float c = -1.0f + 2.0f * (float)i / 15.0f;
        float d = (c - mu_lon[fk]) / expf(ls_lon[fk]);
        klon[i] = expf(-0.5f * d * d);
    } else if (tid < 64) {
        int i = tid - 32;
        float c = -1.0f + 2.0f * (float)i / 31.0f;
        float d = (c - mu_lev[fk]) / expf(ls_lev[fk]);
        klev[i] = expf(-0.5f * d * d);
    } else if (tid < 72) {
        int i = tid - 64;
        float tau = expf(lt_time[fk]) + 1e-6f;
        ktim[i] = expf(-(float)i / tau);
    }
    __syncthreads();

    // Per-lane Bm fragment: pt = lane*4 + j  ->  p = lane>>1 (same for j=0..3),
    // t = (lane&1)*4 + j.
    const float kl = klev[lane >> 1];
    float4 bm4;
    bm4.x = kl * ktim[(lane & 1) * 4 + 0];
    bm4.y = kl * ktim[(lane & 1) * 4 + 1];
    bm4.z = kl * ktim[(lane & 1) * 4 + 2];
    bm4.w = kl * ktim[(lane & 1) * 4 + 3];

    // integral: wave wid handles rows yx = wid*64 .. wid*64+63, coalesced
    float acc = 0.0f;
    #pragma unroll 4
    for (int i = 0; i < 64; ++i) {
        const int yx = wid * 64 + i;                          // wave-uniform
        float4 q4 = *reinterpret_cast<const float4*>(qw + yx * NPT + (lane << 2));
        float s = fmaf(q4.x, bm4.x, fmaf(q4.y, bm4.y, fmaf(q4.z, bm4.z, q4.w * bm4.w)));
        float a = klat[yx >> 4] * klon[yx & 15];              // LDS broadcast
        acc = fmaf(a, s, acc);
    }
    #pragma unroll
    for (int s = 32; s; s >>= 1) acc += __shfl_xor(acc, s, 64);
    if (lane == 0) wred[wid] = acc;
    __syncthreads();
    if (tid == 0) s_inv = 1.0f / (wred[0] + wred[1] + wred[2] + wred[3] + 1e-4f);
    __syncthreads();

    // outputs: Bg coalesced; At transposed (strided scalar writes, tiny)
    Bg[fk * NPT + tid] = klev[tid >> 3] * ktim[tid & 7];
    At[(f * NYX + tid) * NK + k] = klat[tid >> 4] * klon[tid & 15] * s_inv;
}

// ---------------------------------------------------------------------------
// Kernel 2: main streaming reduction. One block = one (b,f).
//   acc4[k] (float4 over this lane's 4 pt's) += A'[k,yx] * (patch*qw)4
//   epilogue: v[k] = dot(acc4[k], Bm4[k]); reduce lanes+waves; direct store.
// 16 FMA per patch element (lower bound) + 1 mul; no atomics, no memset.
// unroll 4 (not 8): 8 outstanding float4 loads/wave is already 6x the
// in-flight bytes needed to saturate per-CU HBM share; unroll 8 risks
// VGPR pressure past 168 (load buffers 64 VGPR + acc 64 VGPR).
// ---------------------------------------------------------------------------
__global__ __launch_bounds__(256) void main_kernel(
    const float* __restrict__ patch,
    const float* __restrict__ qw,
    const float* __restrict__ At,   // [NF][NYX][NK]
    const float* __restrict__ Bg,   // [NF*NK][NPT]
    float* __restrict__ out)
{
    const int bf   = blockIdx.x;    // b*NF + f  (patch is laid out exactly so)
    const int f    = bf & 7;
    const int tid  = threadIdx.x;
    const int lane = tid & 63;
    const int wid  = tid >> 6;

    // Stage A'[f] (16 KB) into LDS: inner-loop reads become uniform
    // ds_read_b128 broadcasts (conflict-free).
    __shared__ float sA[NYX * NK];
    {
        const float4* src = reinterpret_cast<const float4*>(At + f * NYX * NK);
        float4* dst = reinterpret_cast<float4*>(sA);
        #pragma unroll
        for (int j = 0; j < 4; ++j)
            dst[tid + 256 * j] = src[tid + 256 * j];
    }
    __syncthreads();

    float4 acc[NK];
    #pragma unroll
    for (int k = 0; k < NK; ++k) acc[k] = make_float4(0.f, 0.f, 0.f, 0.f);

    const float* pbase = patch + ((size_t)bf << 16);
    const int row0 = wid * 64;     // each wave streams 64 contiguous rows (64 KB)

    #pragma unroll 4
    for (int i = 0; i < 64; ++i) {
        const int yx  = row0 + i;
        const int off = (yx << 8) + (lane << 2);
        float4 p4 = *reinterpret_cast<const float4*>(pbase + off);
        float4 q4 = *reinterpret_cast<const float4*>(qw + off);
        float4 wp;
        wp.x = p4.x * q4.x; wp.y = p4.y * q4.y;
        wp.z = p4.z * q4.z; wp.w = p4.w * q4.w;
        const float4* arow = reinterpret_cast<const float4*>(sA + (yx << 4));
        #pragma unroll
        for (int kq = 0; kq < 4; ++kq) {
            const float4 a4 = arow[kq];     // uniform LDS broadcast
            float4& c0 = acc[kq * 4 + 0];
            float4& c1 = acc[kq * 4 + 1];
            float4& c2 = acc[kq * 4 + 2];
            float4& c3 = acc[kq * 4 + 3];
            c0.x = fmaf(a4.x, wp.x, c0.x); c0.y = fmaf(a4.x, wp.y, c0.y);
            c0.z = fmaf(a4.x, wp.z, c0.z); c0.w = fmaf(a4.x, wp.w, c0.w);
            c1.x = fmaf(a4.y, wp.x, c1.x); c1.y = fmaf(a4.y, wp.y, c1.y);
            c1.z = fmaf(a4.y, wp.z, c1.z); c1.w = fmaf(a4.y, wp.w, c1.w);
            c2.x = fmaf(a4.z, wp.x, c2.x); c2.y = fmaf(a4.z, wp.y, c2.y);
            c2.z = fmaf(a4.z, wp.z, c2.z); c2.w = fmaf(a4.z, wp.w, c2.w);
            c3.x = fmaf(a4.w, wp.x, c3.x); c3.y = fmaf(a4.w, wp.y, c3.y);
            c3.z = fmaf(a4.w, wp.z, c3.z); c3.w = fmaf(a4.w, wp.w, c3.w);
        }
    }

    // Epilogue: dot with Bm fragment, reduce 64 lanes, then 4 waves via LDS.
    __shared__ float red[4][NK];
    float v[NK];
    #pragma unroll
    for (int k = 0; k < NK; ++k) {
        const float4 bm4 = *reinterpret_cast<const float4*>(
            Bg + ((f * NK + k) << 8) + (lane << 2));
        float s = fmaf(acc[k].x, bm4.x, fmaf(acc[k].y, bm4.y,
                  fmaf(acc[k].z, bm4.z, acc[k].w * bm4.w)));
        #pragma unroll
        for (int t = 32; t; t >>= 1) s += __shfl_xor(s, t, 64);
        v[k] = s;
    }
    if (lane == 0) {
        #pragma unroll
        for (int k = 0; k < NK; ++k) red[wid][k] = v[k];
    }
    __syncthreads();
    if (tid < NK)
        out[bf * NK + tid] = red[0][tid] + red[1][tid] + red[2][tid] + red[3][tid];
}

extern "C" void kernel_launch(void* const* d_in, const int* in_sizes, int n_in,
                              void* d_out, int out_size, void* d_ws, size_t ws_size,
                              hipStream_t stream)
{
    const float* patch   = (const float*)d_in[0];
    const float* qw      = (const float*)d_in[1];
    const float* mu_lat  = (const float*)d_in[2];
    const float* ls_lat  = (const float*)d_in[3];
    const float* mu_lon  = (const float*)d_in[4];
    const float* ls_lon  = (const float*)d_in[5];
    const float* mu_lev  = (const float*)d_in[6];
    const float* ls_lev  = (const float*)d_in[7];
    const float* lt_time = (const float*)d_in[8];
    float* out = (float*)d_out;

    float* At = (float*)d_ws;                 // 8*256*16 floats = 128 KiB
    float* Bg = At + NF * NYX * NK;           // 128*256 floats  = 128 KiB

    prep_kernel<<<dim3(NF * NK), dim3(256), 0, stream>>>(
        qw, mu_lat, ls_lat, mu_lon, ls_lon, mu_lev, ls_lev, lt_time, At, Bg);

    main_kernel<<<dim3(NB * NF), dim3(256), 0, stream>>>(patch, qw, At, Bg, out);
}